// Round 2
// baseline (360.404 us; speedup 1.0000x reference)
//
#include <hip/hip_runtime.h>
#include <math.h>

#define NB 8
#define NC 19
#define HH 768
#define WW 768
#define HWSZ (HH*WW)          // 589824
#define OHH 96
#define OWW 96
#define DSN (NB*OHH*OWW)      // 73728
#define MIN_KEPT_DS 1562
#define TOPKK 128
#define IGNV (-100)
#define BLOCKS_PER_SAMPLE 576 // HWSZ / 1024 pixels per block

// ---- workspace layout (bytes) ----
#define HIST1_OFF  0x00000ull   // 8*4096*4 = 131072
#define SUM1_OFF   0x20000ull   // 131072
#define HIST2_OFF  0x40000ull   // 131072
#define SUM2_OFF   0x60000ull   // 131072
#define HIST3_OFF  0x80000ull   // 8*256*4 = 8192
#define SUM3_OFF   0x82000ull   // 8192
#define CTRL_OFF   0x84000ull   // ~320 B
#define ZERO_BYTES 0x84400ull
#define PREDDS_OFF 0x85000ull   // 73728*4 = 294912
#define LOSS_OFF   0xD0000ull   // 8*589824*4 = 18874368
// total ~19.7 MB

struct Ctrl {
  float thr;
  unsigned b1[NB], r1[NB], c1[NB];
  unsigned b2[NB], r2[NB], c2[NB];
  float kth[NB];
  unsigned cnt_gt[NB];
  float sum_gt[NB];
};

__device__ __forceinline__ float fcomp(const float4 a, int j) {
  return (j == 0) ? a.x : (j == 1) ? a.y : (j == 2) ? a.z : a.w;
}

// ---------- Kernel 1: downsampled true-class prob (bilinear over softmax) ----------
__global__ void ds_eval(const float* __restrict__ pred,
                        const int* __restrict__ tgt,
                        float* __restrict__ pred_ds) {
  int idx = blockIdx.x * blockDim.x + threadIdx.x;
  if (idx >= DSN) return;
  int n  = idx / (OHH * OWW);
  int r  = idx % (OHH * OWW);
  int oy = r / OWW, ox = r % OWW;

  const float SY = (float)(767.0 / 95.0);   // align-corners scale (f32, matches ref)
  float cy = (float)oy * SY;
  float cx = (float)ox * SY;
  int y0 = (int)floorf(cy); int y1 = min(y0 + 1, HH - 1); float fy = cy - (float)y0;
  int x0 = (int)floorf(cx); int x1 = min(x0 + 1, WW - 1); float fx = cx - (float)x0;
  int iy = min((int)floorf(cy + 0.5f), HH - 1);
  int ix = min((int)floorf(cx + 0.5f), WW - 1);

  int t = tgt[(size_t)n * HWSZ + (size_t)iy * WW + ix];
  bool valid = (t != IGNV);
  int tc = t < 0 ? 0 : (t > (NC - 1) ? (NC - 1) : t);

  const float* base = pred + (size_t)n * NC * HWSZ;
  int ys[2] = { y0, y1 };
  int xs[2] = { x0, x1 };
  float p[4];
#pragma unroll
  for (int a = 0; a < 2; ++a) {
#pragma unroll
    for (int b = 0; b < 2; ++b) {
      const float* q = base + (size_t)ys[a] * WW + xs[b];
      float m = -INFINITY, lt = 0.0f;
      float v[NC];
#pragma unroll
      for (int c = 0; c < NC; ++c) { v[c] = q[(size_t)c * HWSZ]; m = fmaxf(m, v[c]); }
      float s = 0.0f;
#pragma unroll
      for (int c = 0; c < NC; ++c) {
        s += expf(v[c] - m);
        lt = (c == tc) ? v[c] : lt;
      }
      p[a * 2 + b] = expf(lt - m) / s;
    }
  }
  float py0 = p[0] * (1.0f - fy) + p[2] * fy;
  float py1 = p[1] * (1.0f - fy) + p[3] * fy;
  float out = py0 * (1.0f - fx) + py1 * fx;
  pred_ds[idx] = valid ? out : INFINITY;
}

// ---------- Kernel 2: exact kth-smallest of pred_ds -> threshold ----------
__global__ void select_ds(const float* __restrict__ pred_ds, Ctrl* ctrl) {
  __shared__ unsigned h[4096];
  __shared__ unsigned csum[256];
  __shared__ unsigned sh_b1, sh_b2, sh_r, sh_nv;
  int tid = threadIdx.x;           // 1024 threads
  int bs = blockDim.x;

  // ---- pass A: coarse 12-bit histogram ----
  for (int i = tid; i < 4096; i += bs) h[i] = 0;
  __syncthreads();
  for (int i = tid; i < DSN; i += bs) {
    unsigned u = __float_as_uint(pred_ds[i]);
    atomicAdd(&h[u >> 20], 1u);
  }
  __syncthreads();
  if (tid < 256) {
    unsigned c = 0;
    for (int i = 0; i < 16; ++i) c += h[tid * 16 + i];
    csum[tid] = c;
  }
  __syncthreads();
  if (tid == 0) {
    unsigned nv = DSN - h[0x7F8];       // +inf bin (no NaNs, probs < 2)
    sh_nv = nv;
    unsigned kq = nv < (unsigned)MIN_KEPT_DS ? nv : (unsigned)MIN_KEPT_DS;
    unsigned k0 = kq > 0 ? kq - 1 : 0;  // 0-indexed rank (ascending)
    unsigned cum = 0; int ch = 255;
    for (int k = 0; k < 256; ++k) { if (cum + csum[k] > k0) { ch = k; break; } cum += csum[k]; }
    int bin = ch * 16;
    for (int b = ch * 16; b < ch * 16 + 16; ++b) {
      unsigned cc = h[b];
      if (cum + cc > k0) { bin = b; break; }
      cum += cc;
    }
    sh_b1 = (unsigned)bin;
    sh_r = k0 - cum;                    // 0-indexed rank within bin
  }
  __syncthreads();
  unsigned b1 = sh_b1;

  // ---- pass B: mid 12 bits within bin b1 ----
  for (int i = tid; i < 4096; i += bs) h[i] = 0;
  __syncthreads();
  for (int i = tid; i < DSN; i += bs) {
    unsigned u = __float_as_uint(pred_ds[i]);
    if ((u >> 20) == b1) atomicAdd(&h[(u >> 8) & 0xFFFu], 1u);
  }
  __syncthreads();
  if (tid == 0) {
    unsigned r = sh_r, cum = 0; int bin = 4095;
    for (int b = 0; b < 4096; ++b) {
      unsigned cc = h[b];
      if (cum + cc > r) { bin = b; break; }
      cum += cc;
    }
    sh_b2 = (unsigned)bin;
    sh_r = r - cum;
  }
  __syncthreads();
  unsigned pfx = (b1 << 12) | sh_b2;

  // ---- pass C: low 8 bits ----
  for (int i = tid; i < 256; i += bs) h[i] = 0;
  __syncthreads();
  for (int i = tid; i < DSN; i += bs) {
    unsigned u = __float_as_uint(pred_ds[i]);
    if ((u >> 8) == pfx) atomicAdd(&h[u & 0xFFu], 1u);
  }
  __syncthreads();
  if (tid == 0) {
    unsigned r = sh_r, cum = 0; unsigned bin = 255;
    for (int b = 0; b < 256; ++b) {
      unsigned cc = h[b];
      if (cum + cc > r) { bin = (unsigned)b; break; }
      cum += cc;
    }
    float kthv = __uint_as_float((pfx << 8) | bin);
    float thr = (kthv > 0.7f) ? kthv : 0.7f;
    if ((unsigned)MIN_KEPT_DS >= sh_nv) thr = 1.0f;
    ctrl->thr = thr;
  }
}

// ---------- Kernel 3: main pass — softmax+NLL, loss map + per-sample hist ----------
__global__ __launch_bounds__(256) void main_pass(const float* __restrict__ pred,
                                                 const int* __restrict__ tgt,
                                                 const float* __restrict__ wgt,
                                                 const Ctrl* __restrict__ ctrl,
                                                 unsigned* __restrict__ hist1,
                                                 float* __restrict__ sum1,
                                                 float* __restrict__ loss_full) {
  __shared__ unsigned lh[4096];
  __shared__ float ls[4096];
  for (int i = threadIdx.x; i < 4096; i += 256) { lh[i] = 0; ls[i] = 0.0f; }
  __syncthreads();

  int n = blockIdx.x / BLOCKS_PER_SAMPLE;
  int hw = (blockIdx.x % BLOCKS_PER_SAMPLE) * 1024 + threadIdx.x * 4;
  const float thr = ctrl->thr;

  const float4* pb = (const float4*)(pred + (size_t)n * NC * HWSZ + hw);
  float4 v[NC];
#pragma unroll
  for (int c = 0; c < NC; ++c) v[c] = pb[(size_t)c * (HWSZ / 4)];

  int4 t4 = *(const int4*)(tgt + (size_t)n * HWSZ + hw);
  int tv[4] = { t4.x, t4.y, t4.z, t4.w };
  int tc[4]; bool val[4]; float m[4], s[4], lt[4];
#pragma unroll
  for (int j = 0; j < 4; ++j) {
    val[j] = (tv[j] != IGNV);
    int tcl = tv[j] < 0 ? 0 : (tv[j] > (NC - 1) ? (NC - 1) : tv[j]);
    tc[j] = tcl;
    m[j] = -INFINITY; s[j] = 0.0f; lt[j] = 0.0f;
  }
#pragma unroll
  for (int c = 0; c < NC; ++c) {
#pragma unroll
    for (int j = 0; j < 4; ++j) m[j] = fmaxf(m[j], fcomp(v[c], j));
  }
#pragma unroll
  for (int c = 0; c < NC; ++c) {
#pragma unroll
    for (int j = 0; j < 4; ++j) {
      float x = fcomp(v[c], j);
      s[j] += __expf(x - m[j]);
      lt[j] = (c == tc[j]) ? x : lt[j];
    }
  }

  float4 lo;
  float* lop = (float*)&lo;
#pragma unroll
  for (int j = 0; j < 4; ++j) {
    float d = lt[j] - m[j];
    float p = __expf(d) / s[j];
    float logp = d - __logf(s[j]);
    float nll = -logp * wgt[tc[j]];
    float loss = (val[j] && p <= thr && nll > 0.0f) ? nll : 0.0f;
    lop[j] = loss;
    unsigned u = __float_as_uint(loss);
    atomicAdd(&lh[u >> 20], 1u);
    atomicAdd(&ls[u >> 20], loss);
  }
  *(float4*)(loss_full + (size_t)n * HWSZ + hw) = lo;

  __syncthreads();
  for (int i = threadIdx.x; i < 4096; i += 256) {
    unsigned c = lh[i];
    if (c) {
      atomicAdd(&hist1[(size_t)n * 4096 + i], c);
      atomicAdd(&sum1[(size_t)n * 4096 + i], ls[i]);
    }
  }
}

// ---------- Kernel 4: coarse select (128th largest bin) ----------
__global__ void select1(const unsigned* __restrict__ h, const float* __restrict__ s,
                        Ctrl* ctrl) {
  int n = blockIdx.x, t = threadIdx.x;   // 256 threads
  __shared__ unsigned csum[256];
  __shared__ float fsum[256];
  const unsigned* hb = h + (size_t)n * 4096;
  const float* sb = s + (size_t)n * 4096;
  unsigned c = 0; float f = 0.0f;
  for (int i = 0; i < 16; ++i) { c += hb[t * 16 + i]; f += sb[t * 16 + i]; }
  csum[t] = c; fsum[t] = f;
  __syncthreads();
  if (t == 0) {
    unsigned rank = TOPKK, cum = 0; float sab = 0.0f; int ch = 0;
    for (int k = 255; k >= 0; --k) {
      if (cum + csum[k] >= rank) { ch = k; break; }
      cum += csum[k]; sab += fsum[k];
    }
    int bin = ch * 16;
    for (int b = ch * 16 + 15; b >= ch * 16; --b) {
      unsigned cc = hb[b];
      if (cum + cc >= rank) { bin = b; break; }
      cum += cc; sab += sb[b];
    }
    ctrl->b1[n] = (unsigned)bin;
    ctrl->c1[n] = cum;
    ctrl->r1[n] = rank - cum;
    ctrl->sum_gt[n] = sab;
  }
}

// ---------- Kernel 5: mid-12-bit histogram within selected coarse bin ----------
__global__ void pass2(const float4* __restrict__ loss4, const Ctrl* __restrict__ ctrl,
                      unsigned* __restrict__ hist2, float* __restrict__ sum2) {
  int n = blockIdx.y;
  unsigned b1 = ctrl->b1[n];
  const float4* src = loss4 + (size_t)n * (HWSZ / 4);
  unsigned stride = gridDim.x * blockDim.x;
  for (unsigned i = blockIdx.x * blockDim.x + threadIdx.x; i < HWSZ / 4; i += stride) {
    float4 lv = src[i];
    const float* lp = (const float*)&lv;
#pragma unroll
    for (int j = 0; j < 4; ++j) {
      unsigned u = __float_as_uint(lp[j]);
      if ((u >> 20) == b1) {
        atomicAdd(&hist2[(size_t)n * 4096 + ((u >> 8) & 0xFFFu)], 1u);
        atomicAdd(&sum2[(size_t)n * 4096 + ((u >> 8) & 0xFFFu)], lp[j]);
      }
    }
  }
}

// ---------- Kernel 6: mid select ----------
__global__ void select2(const unsigned* __restrict__ h, const float* __restrict__ s,
                        Ctrl* ctrl) {
  int n = blockIdx.x, t = threadIdx.x;   // 256 threads
  __shared__ unsigned csum[256];
  __shared__ float fsum[256];
  const unsigned* hb = h + (size_t)n * 4096;
  const float* sb = s + (size_t)n * 4096;
  unsigned c = 0; float f = 0.0f;
  for (int i = 0; i < 16; ++i) { c += hb[t * 16 + i]; f += sb[t * 16 + i]; }
  csum[t] = c; fsum[t] = f;
  __syncthreads();
  if (t == 0) {
    unsigned rank = ctrl->r1[n], cum = 0; float sab = 0.0f; int ch = 0;
    for (int k = 255; k >= 0; --k) {
      if (cum + csum[k] >= rank) { ch = k; break; }
      cum += csum[k]; sab += fsum[k];
    }
    int bin = ch * 16;
    for (int b = ch * 16 + 15; b >= ch * 16; --b) {
      unsigned cc = hb[b];
      if (cum + cc >= rank) { bin = b; break; }
      cum += cc; sab += sb[b];
    }
    ctrl->b2[n] = (unsigned)bin;
    ctrl->c2[n] = cum;
    ctrl->r2[n] = rank - cum;
    ctrl->sum_gt[n] += sab;
  }
}

// ---------- Kernel 7: low-8-bit histogram within 24-bit prefix ----------
__global__ void pass3(const float4* __restrict__ loss4, const Ctrl* __restrict__ ctrl,
                      unsigned* __restrict__ hist3, float* __restrict__ sum3) {
  int n = blockIdx.y;
  unsigned pfx = (ctrl->b1[n] << 12) | ctrl->b2[n];
  const float4* src = loss4 + (size_t)n * (HWSZ / 4);
  unsigned stride = gridDim.x * blockDim.x;
  for (unsigned i = blockIdx.x * blockDim.x + threadIdx.x; i < HWSZ / 4; i += stride) {
    float4 lv = src[i];
    const float* lp = (const float*)&lv;
#pragma unroll
    for (int j = 0; j < 4; ++j) {
      unsigned u = __float_as_uint(lp[j]);
      if ((u >> 8) == pfx) {
        atomicAdd(&hist3[(size_t)n * 256 + (u & 0xFFu)], 1u);
        atomicAdd(&sum3[(size_t)n * 256 + (u & 0xFFu)], lp[j]);
      }
    }
  }
}

// ---------- Kernel 8: final select — exact kth + counts ----------
__global__ void select3(const unsigned* __restrict__ h, const float* __restrict__ s,
                        Ctrl* ctrl) {
  int n = blockIdx.x, t = threadIdx.x;   // 256 threads
  __shared__ unsigned hc[256];
  __shared__ float fs[256];
  hc[t] = h[(size_t)n * 256 + t];
  fs[t] = s[(size_t)n * 256 + t];
  __syncthreads();
  if (t == 0) {
    unsigned rank = ctrl->r2[n], cum = 0; float sab = 0.0f; unsigned bin = 0;
    for (int b = 255; b >= 0; --b) {
      unsigned cc = hc[b];
      if (cum + cc >= rank) { bin = (unsigned)b; break; }
      cum += cc; sab += fs[b];
    }
    unsigned bits = (ctrl->b1[n] << 20) | (ctrl->b2[n] << 8) | bin;
    ctrl->kth[n] = __uint_as_float(bits);
    ctrl->cnt_gt[n] = ctrl->c1[n] + ctrl->c2[n] + cum;
    ctrl->sum_gt[n] += sab;
  }
}

// ---------- Kernel 9: finalize scalar ----------
__global__ void finalize(const Ctrl* __restrict__ ctrl, float* __restrict__ out) {
  float acc = 0.0f;
  for (int n = 0; n < NB; ++n) {
    float sum = ctrl->sum_gt[n] +
                (float)(TOPKK - (int)ctrl->cnt_gt[n]) * ctrl->kth[n];
    acc += sum / (float)TOPKK;
  }
  out[0] = acc / (float)NB;
}

extern "C" void kernel_launch(void* const* d_in, const int* in_sizes, int n_in,
                              void* d_out, int out_size, void* d_ws, size_t ws_size,
                              hipStream_t stream) {
  (void)in_sizes; (void)n_in; (void)out_size; (void)ws_size;
  const float* pred = (const float*)d_in[0];
  const float* weight = (const float*)d_in[1];
  const int* tgt = (const int*)d_in[2];        // harness pushes integers as int32
  char* ws = (char*)d_ws;
  unsigned* hist1 = (unsigned*)(ws + HIST1_OFF);
  float*    sum1  = (float*)(ws + SUM1_OFF);
  unsigned* hist2 = (unsigned*)(ws + HIST2_OFF);
  float*    sum2  = (float*)(ws + SUM2_OFF);
  unsigned* hist3 = (unsigned*)(ws + HIST3_OFF);
  float*    sum3  = (float*)(ws + SUM3_OFF);
  Ctrl*     ctrl  = (Ctrl*)(ws + CTRL_OFF);
  float*    pred_ds = (float*)(ws + PREDDS_OFF);
  float*    loss_full = (float*)(ws + LOSS_OFF);

  hipMemsetAsync(d_ws, 0, ZERO_BYTES, stream);

  hipLaunchKernelGGL(ds_eval, dim3((DSN + 255) / 256), dim3(256), 0, stream,
                     pred, tgt, pred_ds);
  hipLaunchKernelGGL(select_ds, dim3(1), dim3(1024), 0, stream, pred_ds, ctrl);
  hipLaunchKernelGGL(main_pass, dim3(NB * BLOCKS_PER_SAMPLE), dim3(256), 0, stream,
                     pred, tgt, weight, ctrl, hist1, sum1, loss_full);
  hipLaunchKernelGGL(select1, dim3(NB), dim3(256), 0, stream, hist1, sum1, ctrl);
  hipLaunchKernelGGL(pass2, dim3(72, NB), dim3(256), 0, stream,
                     (const float4*)loss_full, ctrl, hist2, sum2);
  hipLaunchKernelGGL(select2, dim3(NB), dim3(256), 0, stream, hist2, sum2, ctrl);
  hipLaunchKernelGGL(pass3, dim3(72, NB), dim3(256), 0, stream,
                     (const float4*)loss_full, ctrl, hist3, sum3);
  hipLaunchKernelGGL(select3, dim3(NB), dim3(256), 0, stream, hist3, sum3, ctrl);
  hipLaunchKernelGGL(finalize, dim3(1), dim3(1), 0, stream, ctrl, (float*)d_out);
}